// Round 6
// baseline (388.488 us; speedup 1.0000x reference)
//
#include <hip/hip_runtime.h>
#include <hip/hip_cooperative_groups.h>
#include <math.h>

// HiddenLayer_20126216749058: sparse-GP layer, N=1024, Q=32, M=256, D=32.
// R6: six R5 phase kernels fused into ONE cooperative kernel with 5
//     grid.sync() barriers (launch overhead was ~1/3 of runtime; math is
//     unchanged). Grid sized from occupancy query; work-loops make any
//     grid size correct. Fallback: if cooperative launch fails, the same
//     kernel is launched 6x in per-phase mode (exact R5 behavior).

#define N_PTS 1024
#define QD 32
#define MI 256
#define DOUT 32
#define JITTER 1e-6f
#define LOG2E 1.4426950408889634f
#define LSU 40    // bf16 LDS row stride (80B)
#define ASTR 264  // tmp big-A LDS row stride

namespace cg = cooperative_groups;

typedef short short8 __attribute__((ext_vector_type(8)));
typedef float floatx4 __attribute__((ext_vector_type(4)));
typedef unsigned short ushort;

// ---- workspace layout (float offsets) ----
#define OFF_PSI2S 0           // 65536 zeroed (atomic)
#define OFF_SCOV  65536       // 65536 zeroed (atomic)
#define OFF_GA    131072      // 65536 zeroed (atomic)
#define OFF_S     196608      // 16 scalars zeroed; [8] = done-counter
#define ZERO_CNT  196624
#define OFF_PSI1  196624      // 262144 N*M fp32
#define OFF_P1H   458768      // 131072 N*M bf16
#define OFF_GM    589840      // 262144 N*M fp32 (LOG2E-scaled)
#define OFF_F2    851984      // 32768  N*Q fp32 (LOG2E-scaled)
#define OFF_KM    884752      // 65536
#define OFF_F     950288      // 65536  (E^2)
#define OFF_KINV  1015824     // 65536
#define OFF_KH    1081360     // 32768  M*M bf16
#define OFF_UUT   1114128     // 65536
#define OFF_V1    1179664     // 65536
#define OFF_V     1245200     // 65536
#define OFF_T3    1310736     // 8192   M*D
#define OFF_ZB    1318928     // 4096   M*Q bf16
#define OFF_ABF   1323024     // 131072 N*M bf16
#define OFF_ABFT  1454096     // 131072 M*N bf16
#define OFF_BTJ   1585168     // 1048576 D*M*M bf16 [d][j][l]
#define OFF_BTL   2633744     // 1048576 D*M*M bf16 [d][l][j]
#define OFF_TMP   3682320     // 4194304 N*D*M bf16 [n][d][l]
// end = 7876624 floats = 31.5 MB

struct Params {
  const float *Xm, *Xv, *Z, *ls, *pvar, *pbeta, *qmu, *qs;
  float *psi1, *gm, *f2, *KM, *Fm, *Kinv, *uuT, *V1, *V, *t3;
  float *psi2s, *Scov, *GA, *Sv, *zarea;
  ushort *p1h, *Kh, *zb, *abf, *abfT, *Btj, *Btl, *tmp;
  float *outMean, *outVar, *outL;
};

#define UA 4105
#define UB 1216
#define UC 320
#define UD 160
#define UE 768
#define UF 480

__device__ __forceinline__ ushort f2bf(float x) {
  unsigned int u = __builtin_bit_cast(unsigned int, x);
  u += 0x7fffu + ((u >> 16) & 1u);
  return (ushort)(u >> 16);
}

__device__ __forceinline__ float block_sum256(float s, float* red) {
  #pragma unroll
  for (int off = 32; off >= 1; off >>= 1) s += __shfl_down(s, off, 64);
  int tid = threadIdx.x;
  __syncthreads();
  if ((tid & 63) == 0) red[tid >> 6] = s;
  __syncthreads();
  return (tid == 0) ? (red[0] + red[1] + red[2] + red[3]) : 0.f;
}

// fp32 GEMM 32x32 tile body (C = A@B, 256x256)
__device__ __forceinline__ void gemm32_body(
    float* __restrict__ C, const float* __restrict__ A, const float* __restrict__ B,
    int row0, int col0, float* As, float* Bs, int tid)
{
  int r2 = (tid >> 4)*2, c2 = (tid & 15)*2;
  float a00=0, a01=0, a10=0, a11=0;
  int sr = tid >> 3, sq = (tid & 7)*4;
  for (int kc = 0; kc < 256; kc += 32) {
    float4 av = *(const float4*)&A[(row0+sr)*MI + kc + sq];
    As[(sq+0)*33 + sr] = av.x; As[(sq+1)*33 + sr] = av.y;
    As[(sq+2)*33 + sr] = av.z; As[(sq+3)*33 + sr] = av.w;
    float4 bv = *(const float4*)&B[(kc+sr)*MI + col0 + sq];
    Bs[sr*33 + sq+0] = bv.x; Bs[sr*33 + sq+1] = bv.y;
    Bs[sr*33 + sq+2] = bv.z; Bs[sr*33 + sq+3] = bv.w;
    __syncthreads();
    #pragma unroll
    for (int kk = 0; kk < 32; kk++) {
      float x0 = As[kk*33 + r2], x1 = As[kk*33 + r2 + 1];
      float y0 = Bs[kk*33 + c2], y1 = Bs[kk*33 + c2 + 1];
      a00 += x0*y0; a01 += x0*y1; a10 += x1*y0; a11 += x1*y1;
    }
    __syncthreads();
  }
  int ro = (row0 + r2)*MI + col0 + c2;
  C[ro] = a00; C[ro+1] = a01; C[ro+MI] = a10; C[ro+MI+1] = a11;
}

// C[rbase..rbase+8, 0..32) = A[.,256] @ B[256,32]; Bs = 8192-float LDS
__device__ __forceinline__ void gemmn32_body(
    float* __restrict__ C, const float* __restrict__ A, const float* __restrict__ B,
    int rbase, float* Bs, int tid)
{
  for (int i = tid; i < 8192; i += 256) Bs[i] = B[i];
  __syncthreads();
  int c = tid & 31, r = rbase + (tid >> 5);
  float acc = 0;
  for (int k = 0; k < 256; k += 4) {
    float4 a4 = *(const float4*)&A[r*256 + k];
    acc += a4.x*Bs[(k+0)*32+c] + a4.y*Bs[(k+1)*32+c]
         + a4.z*Bs[(k+2)*32+c] + a4.w*Bs[(k+3)*32+c];
  }
  C[r*32 + c] = acc;
  __syncthreads();
}

// ===== Phase A: stats | Kmm | zero | zb | btj | btl =====
__device__ void phaseA(int bx, int tid, float* sb, const Params& p) {
  if (bx < N_PTS) {
    int n = bx;
    float* w1s = sb; float* w1mu = sb+32; float* w2s = sb+64; float* w2mu = sb+96;
    float* rl2s = sb+128; float* la1 = sb+160; float* a1s = sb+192;
    float* la2 = sb+224; float* a2s = sb+256;
    float v = *p.pvar;
    if (tid < QD) {
      int q = tid;
      float s = p.Xv[n*QD+q], mu = p.Xm[n*QD+q], l = p.ls[q], l2 = l*l;
      float rl2 = 1.f/l2;
      float d1 = l2 + s, d2 = l2 + 2.f*s;
      float iw1 = 1.f/d1, iw2 = 1.f/d2;
      w1s[q] = iw1; w1mu[q] = iw1*mu; w2s[q] = iw2; w2mu[q] = iw2*mu; rl2s[q] = rl2;
      la1[q] = logf(d1*rl2); a1s[q] = mu*mu*iw1;
      la2[q] = logf(d2*rl2); a2s[q] = mu*mu*iw2;
      p.f2[n*QD+q] = LOG2E*0.5f*(rl2 - iw2);
    }
    __syncthreads();
    if (tid == 0) {
      float s1=0, s2=0, s3=0, s4=0;
      for (int q = 0; q < QD; q++) { s1 += la1[q]; s2 += a1s[q]; s3 += la2[q]; s4 += a2s[q]; }
      sb[288] = -0.5f*(s1 + s2);
      sb[289] = 2.f*logf(v) - 0.5f*s3 - s4;
    }
    __syncthreads();
    float c1sh = sb[288], c2sh = sb[289];
    int m = tid;
    float b1 = 0, c1a = 0, eb = 0, ec = 0, zsq = 0;
    #pragma unroll
    for (int q4 = 0; q4 < QD; q4 += 4) {
      float4 z4 = *(const float4*)&p.Z[m*QD + q4];
      float z, zz;
      z = z4.x; zz = z*z; b1 += w1mu[q4+0]*z; c1a += w1s[q4+0]*zz; eb += w2mu[q4+0]*z; ec += w2s[q4+0]*zz; zsq += rl2s[q4+0]*zz;
      z = z4.y; zz = z*z; b1 += w1mu[q4+1]*z; c1a += w1s[q4+1]*zz; eb += w2mu[q4+1]*z; ec += w2s[q4+1]*zz; zsq += rl2s[q4+1]*zz;
      z = z4.z; zz = z*z; b1 += w1mu[q4+2]*z; c1a += w1s[q4+2]*zz; eb += w2mu[q4+2]*z; ec += w2s[q4+2]*zz; zsq += rl2s[q4+2]*zz;
      z = z4.w; zz = z*z; b1 += w1mu[q4+3]*z; c1a += w1s[q4+3]*zz; eb += w2mu[q4+3]*z; ec += w2s[q4+3]*zz; zsq += rl2s[q4+3]*zz;
    }
    float pv = v * __expf(c1sh + b1 - 0.5f*c1a);
    p.psi1[n*MI + m] = pv;
    p.p1h[n*MI + m] = f2bf(pv);
    p.gm[n*MI + m] = LOG2E*(0.5f*c2sh + (eb - 0.25f*ec) - 0.25f*zsq);
    __syncthreads();
  } else if (bx < N_PTS + MI) {
    int m = bx - N_PTS;
    if (tid < QD) { float l = p.ls[tid]; sb[tid] = 1.f/(l*l); }
    __syncthreads();
    int k = tid;
    float acc = 0;
    #pragma unroll
    for (int q4 = 0; q4 < QD; q4 += 4) {
      float4 zm = *(const float4*)&p.Z[m*QD + q4];
      float4 zk = *(const float4*)&p.Z[k*QD + q4];
      float d;
      d = zm.x - zk.x; acc += d*d*sb[q4+0];
      d = zm.y - zk.y; acc += d*d*sb[q4+1];
      d = zm.z - zk.z; acc += d*d*sb[q4+2];
      d = zm.w - zk.w; acc += d*d*sb[q4+3];
    }
    float v = *p.pvar;
    p.KM[m*MI + k] = v*__expf(-0.5f*acc) + (m == k ? JITTER : 0.f);
    __syncthreads();
  } else if (bx < N_PTS + MI + 769) {
    int i = (bx - N_PTS - MI)*256 + tid;
    if (i < ZERO_CNT) p.zarea[i] = 0.f;
  } else if (bx < N_PTS + MI + 769 + 8) {
    int i = ((bx - N_PTS - MI - 769)*256 + tid)*4;
    float4 z = *(const float4*)&p.Z[i];
    uint2 o;
    o.x = (unsigned)f2bf(z.x) | ((unsigned)f2bf(z.y) << 16);
    o.y = (unsigned)f2bf(z.z) | ((unsigned)f2bf(z.w) << 16);
    *(uint2*)&p.zb[i] = o;
  } else if (bx < 3081) {
    int idx = bx - 2057;
    int j = idx & 255, l0 = (idx >> 8)*64;
    int base = j*8192 + l0*32;
    #pragma unroll
    for (int e = 0; e < 8; e++) {
      int lin = e*256 + tid;
      sb[(lin >> 5)*33 + (lin & 31)] = p.qs[base + lin];
    }
    __syncthreads();
    int ll = tid & 63, kq = tid >> 6;
    int l = l0 + ll;
    #pragma unroll
    for (int w8 = 0; w8 < 8; w8++) {
      int k = kq*8 + w8;
      float v = (l <= j) ? sb[ll*33 + k] : 0.f;
      p.Btj[k*65536 + j*256 + l] = f2bf(v);
    }
    __syncthreads();
  } else {
    int idx = bx - 3081;
    int l = idx & 255, j0 = (idx >> 8)*64;
    {
      int jr = tid >> 2, d8 = (tid & 3)*8;
      const float* src = &p.qs[(j0+jr)*8192 + l*32 + d8];
      float4 a = *(const float4*)src, b = *(const float4*)(src+4);
      float* dst = &sb[jr*33 + d8];
      dst[0]=a.x; dst[1]=a.y; dst[2]=a.z; dst[3]=a.w;
      dst[4]=b.x; dst[5]=b.y; dst[6]=b.z; dst[7]=b.w;
    }
    __syncthreads();
    int d = tid >> 3, j8 = (tid & 7)*8;
    unsigned int pk[4];
    #pragma unroll
    for (int q = 0; q < 4; q++) {
      int ja = j0 + j8 + q*2;
      float va = (l <= ja)   ? sb[(j8 + q*2)*33 + d]     : 0.f;
      float vb = (l <= ja+1) ? sb[(j8 + q*2 + 1)*33 + d] : 0.f;
      pk[q] = (unsigned)f2bf(va) | ((unsigned)f2bf(vb) << 16);
    }
    *(uint4*)&p.Btl[d*65536 + l*256 + j0 + j8] = make_uint4(pk[0], pk[1], pk[2], pk[3]);
    __syncthreads();
  }
}

// ===== Phase B: psi2 | NS1 (F=E@E) | scov gram =====
__device__ void phaseB(int bx, int tid, float* sb, const Params& p) {
  int lane = tid & 63, w = tid >> 6, l15 = lane & 15, quad = lane >> 4;
  if (bx < 1024) {
    int tile = bx & 15;
    int tm = (tile & 3)*64, tk = (tile >> 2)*64;
    int n0 = (bx >> 4)*16;
    float zm[8];
    {
      const float* zr = &p.Z[(tm + w*16 + l15)*32 + quad*8];
      float4 aq = *(const float4*)zr, bq = *(const float4*)(zr + 4);
      zm[0]=aq.x; zm[1]=aq.y; zm[2]=aq.z; zm[3]=aq.w;
      zm[4]=bq.x; zm[5]=bq.y; zm[6]=bq.z; zm[7]=bq.w;
    }
    short8 bfr[4];
    #pragma unroll
    for (int c = 0; c < 4; c++)
      bfr[c] = *(const short8*)&p.zb[(tk + c*16 + l15)*32 + quad*8];
    float accs[4][4] = {};
    #pragma unroll 1
    for (int nl = 0; nl < 16; nl++) {
      int n = n0 + nl;
      const float* fp = &p.f2[n*32 + quad*8];
      float4 f0 = *(const float4*)fp, f1 = *(const float4*)(fp + 4);
      unsigned q0 = (unsigned)f2bf(f0.x*zm[0]) | ((unsigned)f2bf(f0.y*zm[1]) << 16);
      unsigned q1 = (unsigned)f2bf(f0.z*zm[2]) | ((unsigned)f2bf(f0.w*zm[3]) << 16);
      unsigned q2 = (unsigned)f2bf(f1.x*zm[4]) | ((unsigned)f2bf(f1.y*zm[5]) << 16);
      unsigned q3 = (unsigned)f2bf(f1.z*zm[6]) | ((unsigned)f2bf(f1.w*zm[7]) << 16);
      uint4 u4 = make_uint4(q0, q1, q2, q3);
      short8 af = __builtin_bit_cast(short8, u4);
      float4 gmv = *(const float4*)&p.gm[n*256 + tm + w*16 + quad*4];
      float gmr[4] = {gmv.x, gmv.y, gmv.z, gmv.w};
      #pragma unroll
      for (int c = 0; c < 4; c++) {
        floatx4 zz = {0.f, 0.f, 0.f, 0.f};
        floatx4 g = __builtin_amdgcn_mfma_f32_16x16x32_bf16(af, bfr[c], zz, 0, 0, 0);
        float gk = p.gm[n*256 + tk + c*16 + l15];
        #pragma unroll
        for (int r = 0; r < 4; r++)
          accs[c][r] += __builtin_exp2f(g[r] + gmr[r] + gk);
      }
    }
    #pragma unroll
    for (int c = 0; c < 4; c++)
      #pragma unroll
      for (int r = 0; r < 4; r++)
        atomicAdd(&p.psi2s[(tm + w*16 + quad*4 + r)*256 + tk + c*16 + l15], accs[c][r]);
  } else if (bx < 1088) {
    int idx = bx - 1024;
    int col0 = (idx & 7)*32, row0 = (idx >> 3)*32;
    float s = 1.f/(p.pvar[0] + JITTER);
    float* As = sb; float* Bs = sb + 1056;
    int r2 = (tid >> 4)*2, c2 = (tid & 15)*2;
    float a00=0, a01=0, a10=0, a11=0;
    int sr = tid >> 3, sq = (tid & 7)*4;
    for (int kc = 0; kc < 256; kc += 32) {
      int ar = row0 + sr;
      float4 av = *(const float4*)&p.KM[ar*MI + kc + sq];
      av.x = s*av.x - (ar == kc+sq+0 ? 1.f : 0.f);
      av.y = s*av.y - (ar == kc+sq+1 ? 1.f : 0.f);
      av.z = s*av.z - (ar == kc+sq+2 ? 1.f : 0.f);
      av.w = s*av.w - (ar == kc+sq+3 ? 1.f : 0.f);
      As[(sq+0)*33 + sr] = av.x; As[(sq+1)*33 + sr] = av.y;
      As[(sq+2)*33 + sr] = av.z; As[(sq+3)*33 + sr] = av.w;
      int br = kc + sr;
      float4 bv = *(const float4*)&p.KM[br*MI + col0 + sq];
      bv.x = s*bv.x - (br == col0+sq+0 ? 1.f : 0.f);
      bv.y = s*bv.y - (br == col0+sq+1 ? 1.f : 0.f);
      bv.z = s*bv.z - (br == col0+sq+2 ? 1.f : 0.f);
      bv.w = s*bv.w - (br == col0+sq+3 ? 1.f : 0.f);
      Bs[sr*33 + sq+0] = bv.x; Bs[sr*33 + sq+1] = bv.y;
      Bs[sr*33 + sq+2] = bv.z; Bs[sr*33 + sq+3] = bv.w;
      __syncthreads();
      #pragma unroll
      for (int kk = 0; kk < 32; kk++) {
        float x0 = As[kk*33 + r2], x1 = As[kk*33 + r2 + 1];
        float y0 = Bs[kk*33 + c2], y1 = Bs[kk*33 + c2 + 1];
        a00 += x0*y0; a01 += x0*y1; a10 += x1*y0; a11 += x1*y1;
      }
      __syncthreads();
    }
    int ro = (row0 + r2)*MI + col0 + c2;
    p.Fm[ro] = a00; p.Fm[ro+1] = a01; p.Fm[ro+MI] = a10; p.Fm[ro+MI+1] = a11;
  } else {
    int idx = bx - 1088;
    int tile = idx & 15;
    int i0 = (tile & 3)*64, j0 = (tile >> 2)*64;
    int d0 = (idx >> 4)*4;
    ushort* Au = (ushort*)sb; ushort* Bu = Au + 2560;
    floatx4 accs[4];
    #pragma unroll
    for (int c = 0; c < 4; c++) accs[c] = (floatx4){0.f,0.f,0.f,0.f};
    int sr = tid >> 2, sq = (tid & 3)*8;
    for (int dd = 0; dd < 4; dd++) {
      const ushort* base = p.Btj + (size_t)(d0 + dd)*65536;
      for (int kc = 0; kc < 256; kc += 32) {
        __syncthreads();
        *(uint4*)&Au[sr*LSU + sq] = *(const uint4*)&base[(i0+sr)*256 + kc + sq];
        *(uint4*)&Bu[sr*LSU + sq] = *(const uint4*)&base[(j0+sr)*256 + kc + sq];
        __syncthreads();
        short8 af = *(const short8*)&Au[(w*16 + l15)*LSU + quad*8];
        #pragma unroll
        for (int c = 0; c < 4; c++) {
          short8 bfv = *(const short8*)&Bu[(c*16 + l15)*LSU + quad*8];
          accs[c] = __builtin_amdgcn_mfma_f32_16x16x32_bf16(af, bfv, accs[c], 0, 0, 0);
        }
      }
    }
    #pragma unroll
    for (int c = 0; c < 4; c++)
      #pragma unroll
      for (int r = 0; r < 4; r++)
        atomicAdd(&p.Scov[(i0 + w*16 + quad*4 + r)*256 + j0 + c*16 + l15], accs[c][r]);
  }
}

// ===== Phase C: NS2 (Kinv + Kh) | uuT =====
__device__ void phaseC(int bx, int tid, float* sb, const Params& p) {
  if (bx < 64) {
    int col0 = (bx & 7)*32, row0 = (bx >> 3)*32;
    float s = 1.f/(p.pvar[0] + JITTER);
    float* As = sb; float* Bs = sb + 1056;
    int r2 = (tid >> 4)*2, c2 = (tid & 15)*2;
    float a00=0, a01=0, a10=0, a11=0;
    int sr = tid >> 3, sq = (tid & 7)*4;
    for (int kc = 0; kc < 256; kc += 32) {
      int ar = row0 + sr;
      float4 av = *(const float4*)&p.Fm[ar*MI + kc + sq];
      As[(sq+0)*33 + sr] = av.x; As[(sq+1)*33 + sr] = av.y;
      As[(sq+2)*33 + sr] = av.z; As[(sq+3)*33 + sr] = av.w;
      int br = kc + sr;
      float4 bv = *(const float4*)&p.KM[br*MI + col0 + sq];
      bv.x = (br == col0+sq+0 ? 2.f : 0.f) - s*bv.x;
      bv.y = (br == col0+sq+1 ? 2.f : 0.f) - s*bv.y;
      bv.z = (br == col0+sq+2 ? 2.f : 0.f) - s*bv.z;
      bv.w = (br == col0+sq+3 ? 2.f : 0.f) - s*bv.w;
      Bs[sr*33 + sq+0] = bv.x; Bs[sr*33 + sq+1] = bv.y;
      Bs[sr*33 + sq+2] = bv.z; Bs[sr*33 + sq+3] = bv.w;
      __syncthreads();
      #pragma unroll
      for (int kk = 0; kk < 32; kk++) {
        float x0 = As[kk*33 + r2], x1 = As[kk*33 + r2 + 1];
        float y0 = Bs[kk*33 + c2], y1 = Bs[kk*33 + c2 + 1];
        a00 += x0*y0; a01 += x0*y1; a10 += x1*y0; a11 += x1*y1;
      }
      __syncthreads();
    }
    float vals[2][2] = {{a00, a01}, {a10, a11}};
    #pragma unroll
    for (int i = 0; i < 2; i++)
      #pragma unroll
      for (int j = 0; j < 2; j++) {
        int R = row0 + r2 + i, C = col0 + c2 + j;
        float kv = s*(vals[i][j] + (R == C ? 2.f : 0.f) - s*p.KM[R*MI + C]);
        p.Kinv[R*MI + C] = kv;
        p.Kh[R*MI + C] = f2bf(kv);
      }
  } else {
    int i = bx - 64, j = tid;
    float acc = 0;
    #pragma unroll
    for (int d = 0; d < DOUT; d++) acc += p.qmu[i*DOUT + d]*p.qmu[j*DOUT + d];
    p.uuT[i*MI + j] = p.Scov[i*MI + j] + acc;
  }
}

// ===== Phase D: abf = psi1@Kinv (bf16) | t3 | V1 =====
__device__ void phaseD(int bx, int tid, float* sb, const Params& p) {
  if (bx < 64) {
    int j0 = (bx & 3)*64, n0 = (bx >> 2)*64;
    int lane = tid & 63, w = tid >> 6, l15 = lane & 15, quad = lane >> 4;
    ushort* Ah = (ushort*)sb; ushort* Bh = Ah + 2560;
    floatx4 acc[4];
    #pragma unroll
    for (int c = 0; c < 4; c++) acc[c] = (floatx4){0.f,0.f,0.f,0.f};
    int sr = tid >> 2, sq = (tid & 3)*8;
    for (int kc = 0; kc < 256; kc += 32) {
      __syncthreads();
      *(uint4*)&Ah[sr*LSU + sq] = *(const uint4*)&p.p1h[(n0+sr)*256 + kc + sq];
      *(uint4*)&Bh[sr*LSU + sq] = *(const uint4*)&p.Kh[(j0+sr)*256 + kc + sq];
      __syncthreads();
      short8 ah = *(const short8*)&Ah[(w*16 + l15)*LSU + quad*8];
      #pragma unroll
      for (int c = 0; c < 4; c++) {
        short8 bh = *(const short8*)&Bh[(c*16 + l15)*LSU + quad*8];
        acc[c] = __builtin_amdgcn_mfma_f32_16x16x32_bf16(ah, bh, acc[c], 0, 0, 0);
      }
    }
    #pragma unroll
    for (int c = 0; c < 4; c++)
      #pragma unroll
      for (int r = 0; r < 4; r++) {
        int n = n0 + w*16 + quad*4 + r, j = j0 + c*16 + l15;
        ushort hv = f2bf(acc[c][r]);
        p.abf[n*256 + j] = hv;
        p.abfT[j*1024 + n] = hv;
      }
    __syncthreads();
  } else if (bx < 96) {
    gemmn32_body(p.t3, p.Kinv, p.qmu, (bx - 64)*8, sb, tid);
  } else {
    int idx = bx - 96;
    gemm32_body(p.V1, p.Kinv, p.uuT, (idx >> 3)*32, (idx & 7)*32, sb, sb + 1056, tid);
  }
}

// ===== Phase E: tmp | GA gram | V | forward_mean =====
__device__ void phaseE(int bx, int tid, float* sb, const Params& p) {
  int lane = tid & 63, w = tid >> 6, l15 = lane & 15, quad = lane >> 4;
  if (bx < 512) {
    int l0 = (bx & 3)*64, n0 = ((bx >> 2) & 15)*64, dg = (bx >> 6)*4;
    ushort* As = (ushort*)sb; ushort* Bs = As + 16896;
    __syncthreads();
    #pragma unroll
    for (int e = 0; e < 8; e++) {
      int lin = e*256 + tid;
      int row = lin >> 5, c8 = (lin & 31)*8;
      *(uint4*)&As[row*ASTR + c8] = *(const uint4*)&p.abf[(n0+row)*256 + c8];
    }
    int sr = tid >> 2, sq = (tid & 3)*8;
    for (int dd = 0; dd < 4; dd++) {
      int d = dg + dd;
      floatx4 acc[4];
      #pragma unroll
      for (int c = 0; c < 4; c++) acc[c] = (floatx4){0.f,0.f,0.f,0.f};
      for (int kc = 0; kc < 256; kc += 32) {
        __syncthreads();
        *(uint4*)&Bs[sr*LSU + sq] = *(const uint4*)&p.Btl[(size_t)d*65536 + (l0+sr)*256 + kc + sq];
        __syncthreads();
        short8 af = *(const short8*)&As[(w*16 + l15)*ASTR + kc + quad*8];
        #pragma unroll
        for (int c = 0; c < 4; c++) {
          short8 b = *(const short8*)&Bs[(c*16 + l15)*LSU + quad*8];
          acc[c] = __builtin_amdgcn_mfma_f32_16x16x32_bf16(af, b, acc[c], 0, 0, 0);
        }
      }
      #pragma unroll
      for (int c = 0; c < 4; c++)
        #pragma unroll
        for (int r = 0; r < 4; r++) {
          int n = n0 + w*16 + quad*4 + r, l = l0 + c*16 + l15;
          p.tmp[(size_t)n*8192 + (size_t)d*256 + l] = f2bf(acc[c][r]);
        }
    }
    __syncthreads();
  } else if (bx < 576) {
    int idx = bx - 512;
    int tile = idx & 15;
    int i0 = (tile & 3)*64, j0 = (tile >> 2)*64;
    int nc0 = (idx >> 4)*256;
    ushort* Au = (ushort*)sb; ushort* Bu = Au + 2560;
    floatx4 accs[4];
    #pragma unroll
    for (int c = 0; c < 4; c++) accs[c] = (floatx4){0.f,0.f,0.f,0.f};
    int sr = tid >> 2, sq = (tid & 3)*8;
    for (int kc = 0; kc < 256; kc += 32) {
      __syncthreads();
      *(uint4*)&Au[sr*LSU + sq] = *(const uint4*)&p.abfT[(i0+sr)*1024 + nc0 + kc + sq];
      *(uint4*)&Bu[sr*LSU + sq] = *(const uint4*)&p.abfT[(j0+sr)*1024 + nc0 + kc + sq];
      __syncthreads();
      short8 af = *(const short8*)&Au[(w*16 + l15)*LSU + quad*8];
      #pragma unroll
      for (int c = 0; c < 4; c++) {
        short8 bfv = *(const short8*)&Bu[(c*16 + l15)*LSU + quad*8];
        accs[c] = __builtin_amdgcn_mfma_f32_16x16x32_bf16(af, bfv, accs[c], 0, 0, 0);
      }
    }
    #pragma unroll
    for (int c = 0; c < 4; c++)
      #pragma unroll
      for (int r = 0; r < 4; r++)
        atomicAdd(&p.GA[(i0 + w*16 + quad*4 + r)*256 + j0 + c*16 + l15], accs[c][r]);
  } else if (bx < 640) {
    int idx = bx - 576;
    gemm32_body(p.V, p.V1, p.Kinv, (idx >> 3)*32, (idx & 7)*32, sb, sb + 1056, tid);
  } else {
    gemmn32_body(p.outMean, p.psi1, p.t3, (bx - 640)*8, sb, tid);
  }
}

// ===== Phase F: fvar | reductions + finalize =====
__device__ void phaseF(int bx, int tid, float* sb, const Params& p) {
  if (bx < 256) {
    int lane = tid & 63, w = tid >> 6;
    int n = bx*4 + w;
    int l15 = lane & 15, quad = lane >> 4;
    floatx4 acc[2][2];
    #pragma unroll
    for (int i = 0; i < 2; i++)
      #pragma unroll
      for (int j = 0; j < 2; j++) acc[i][j] = (floatx4){0.f,0.f,0.f,0.f};
    size_t base = (size_t)n*8192;
    #pragma unroll 1
    for (int s8 = 0; s8 < 8; s8++) {
      int off = s8*32 + quad*8;
      short8 h0 = *(const short8*)&p.tmp[base + l15*256 + off];
      short8 h1 = *(const short8*)&p.tmp[base + (16 + l15)*256 + off];
      acc[0][0] = __builtin_amdgcn_mfma_f32_16x16x32_bf16(h0, h0, acc[0][0], 0,0,0);
      acc[0][1] = __builtin_amdgcn_mfma_f32_16x16x32_bf16(h0, h1, acc[0][1], 0,0,0);
      acc[1][0] = __builtin_amdgcn_mfma_f32_16x16x32_bf16(h1, h0, acc[1][0], 0,0,0);
      acc[1][1] = __builtin_amdgcn_mfma_f32_16x16x32_bf16(h1, h1, acc[1][1], 0,0,0);
    }
    float ib = 1.f / (*p.pbeta);
    #pragma unroll
    for (int I = 0; I < 2; I++)
      #pragma unroll
      for (int J = 0; J < 2; J++)
        #pragma unroll
        for (int r = 0; r < 4; r++) {
          int row = I*16 + quad*4 + r, col = J*16 + l15;
          p.outVar[(size_t)n*1024 + row*32 + col] = acc[I][J][r] + (row == col ? ib : 0.f);
        }
  } else {
    int idx = bx - 256;
    int seg = idx >> 5;
    int i0 = (idx & 31)*256 + tid;
    const int stride = 32*256;
    float s = 0;
    int target = 0;
    if (seg == 0) { for (int i = i0; i < 65536; i += stride) s += p.Kinv[i]*p.psi2s[i]; target = 0; }
    else if (seg == 1) { for (int i = i0; i < 8192; i += stride) s += p.qmu[i]*p.t3[i]; target = 1; }
    else if (seg == 2) { for (int i = i0; i < 65536; i += stride) s += p.Kinv[i]*p.Scov[i]; target = 2; }
    else if (seg == 3) {
      float invc = 1.f/(*p.pvar + JITTER);
      for (int i = i0; i < 65536; i += stride) {
        int r = i >> 8, c = i & 255;
        if (r != c) { float e = p.KM[i]*invc; s += e*e; }
      }
      target = 4;
    }
    else if (seg == 4) {
      for (int i = i0; i < MI*DOUT; i += stride) {
        int m = i >> 5, k = i & 31;
        float dq = p.qs[m*8224 + k];   // (m*256+m)*32 + k
        s += logf(dq*dq);
      }
      target = 5;
    }
    else if (seg == 5) { for (int i = i0; i < 65536; i += stride) s += p.psi2s[i]*p.V[i]; target = 6; }
    else { for (int i = i0; i < 65536; i += stride) s += p.GA[i]*p.uuT[i]; target = 7; }
    float bs = block_sum256(s, sb);
    if (tid == 0) {
      atomicAdd(&p.Sv[target], bs);
      __threadfence();
      unsigned prev = atomicAdd((unsigned int*)&p.Sv[8], 1u);
      if (prev == 223u) {
        float S0 = atomicAdd(&p.Sv[0], 0.f);
        float S1 = atomicAdd(&p.Sv[1], 0.f);
        float S2 = atomicAdd(&p.Sv[2], 0.f);
        float S4 = atomicAdd(&p.Sv[4], 0.f);
        float S5 = atomicAdd(&p.Sv[5], 0.f);
        float S6 = atomicAdd(&p.Sv[6], 0.f);
        float S7 = atomicAdd(&p.Sv[7], 0.f);
        float v = *p.pvar, b = *p.pbeta;
        float trace = (float)N_PTS * v - S0;
        float lml = -0.5f * b * (float)DOUT * trace;
        float c = v + JITTER;
        float logdetK = (float)MI * logf(c) - 0.5f * S4;
        float kl = 0.5f*(S1 + S2 - (float)(MI*DOUT) + (float)DOUT*logdetK - S5);
        lml -= kl;
        lml -= 0.5f * b * (S6 - S7);
        p.outL[0] = lml;
      }
    }
  }
}

__device__ __forceinline__ void run_phase(int ph, int units, const Params& p, float* sb) {
  int tid = threadIdx.x;
  for (int u = blockIdx.x; u < units; u += gridDim.x) {
    switch (ph) {
      case 0: phaseA(u, tid, sb, p); break;
      case 1: phaseB(u, tid, sb, p); break;
      case 2: phaseC(u, tid, sb, p); break;
      case 3: phaseD(u, tid, sb, p); break;
      case 4: phaseE(u, tid, sb, p); break;
      default: phaseF(u, tid, sb, p); break;
    }
    __syncthreads();
  }
}

__global__ __launch_bounds__(256) void mega(Params p, int phase) {
  __shared__ __align__(16) float sb[9728];
  const int units[6] = {UA, UB, UC, UD, UE, UF};
  if (phase < 0) {
    cg::grid_group g = cg::this_grid();
    run_phase(0, UA, p, sb); g.sync();
    run_phase(1, UB, p, sb); g.sync();
    run_phase(2, UC, p, sb); g.sync();
    run_phase(3, UD, p, sb); g.sync();
    run_phase(4, UE, p, sb); g.sync();
    run_phase(5, UF, p, sb);
  } else {
    run_phase(phase, units[phase], p, sb);
  }
}

extern "C" void kernel_launch(void* const* d_in, const int* in_sizes, int n_in,
                              void* d_out, int out_size, void* d_ws, size_t ws_size,
                              hipStream_t stream) {
  (void)in_sizes; (void)n_in; (void)out_size; (void)ws_size;
  float* out = (float*)d_out;
  float* ws  = (float*)d_ws;

  Params p;
  p.Xm = (const float*)d_in[0];
  p.Xv = (const float*)d_in[1];
  p.Z  = (const float*)d_in[2];
  p.qmu = (const float*)d_in[3];
  p.qs  = (const float*)d_in[4];
  p.ls  = (const float*)d_in[5];
  p.pvar  = (const float*)d_in[6];
  p.pbeta = (const float*)d_in[7];
  p.psi2s = ws + OFF_PSI2S;
  p.Scov  = ws + OFF_SCOV;
  p.GA    = ws + OFF_GA;
  p.Sv    = ws + OFF_S;
  p.zarea = ws;
  p.psi1  = ws + OFF_PSI1;
  p.p1h   = (ushort*)(ws + OFF_P1H);
  p.gm    = ws + OFF_GM;
  p.f2    = ws + OFF_F2;
  p.KM    = ws + OFF_KM;
  p.Fm    = ws + OFF_F;
  p.Kinv  = ws + OFF_KINV;
  p.Kh    = (ushort*)(ws + OFF_KH);
  p.uuT   = ws + OFF_UUT;
  p.V1    = ws + OFF_V1;
  p.V     = ws + OFF_V;
  p.t3    = ws + OFF_T3;
  p.zb    = (ushort*)(ws + OFF_ZB);
  p.abf   = (ushort*)(ws + OFF_ABF);
  p.abfT  = (ushort*)(ws + OFF_ABFT);
  p.Btj   = (ushort*)(ws + OFF_BTJ);
  p.Btl   = (ushort*)(ws + OFF_BTL);
  p.tmp   = (ushort*)(ws + OFF_TMP);
  p.outMean = out;
  p.outVar  = out + 32768;
  p.outL    = out + 32768 + 1048576;

  int occ = 0;
  hipError_t qe = hipOccupancyMaxActiveBlocksPerMultiprocessor(&occ, mega, 256, 0);
  if (qe != hipSuccess || occ < 1) occ = 1;
  int grid = occ * 256;
  if (grid > 1024) grid = 1024;

  int phase = -1;
  void* args[] = {(void*)&p, (void*)&phase};
  hipError_t le = hipLaunchCooperativeKernel(mega, dim3(grid), dim3(256),
                                             args, 0, stream);
  if (le != hipSuccess) {
    // fallback: per-phase launches (exact R5 behavior)
    mega<<<UA, 256, 0, stream>>>(p, 0);
    mega<<<UB, 256, 0, stream>>>(p, 1);
    mega<<<UC, 256, 0, stream>>>(p, 2);
    mega<<<UD, 256, 0, stream>>>(p, 3);
    mega<<<UE, 256, 0, stream>>>(p, 4);
    mega<<<UF, 256, 0, stream>>>(p, 5);
  }
}

// Round 7
// 178.835 us; speedup vs baseline: 2.1723x; 2.1723x over previous
//
#include <hip/hip_runtime.h>
#include <math.h>

// HiddenLayer_20126216749058: sparse-GP layer, N=1024, Q=32, M=256, D=32.
// R7: revert R6's cooperative mega-kernel (grid.sync on gfx950 drains the
//     per-XCD L2s -> 100MB HBM re-reads, 295us). Back to multi-launch, now
//     5 phases: Kinv = s(I-E+E^2) folded into B's GEMM epilogue (3-term NS,
//     residual ~1e-6 abs vs 3276 budget); uuT eliminated via trace identity
//     (W = Kinv psi2s Kinv; uuT = Scov + qmu qmu^T inline in reductions);
//     tmp as plain 2048-block bf16 GEMM (16 barriers/blk, 10KB LDS).

#define N_PTS 1024
#define QD 32
#define MI 256
#define DOUT 32
#define JITTER 1e-6f
#define LOG2E 1.4426950408889634f
#define LSU 40    // bf16 LDS row stride (80B)

typedef short short8 __attribute__((ext_vector_type(8)));
typedef float floatx4 __attribute__((ext_vector_type(4)));
typedef unsigned short ushort;

// ---- workspace layout (float offsets) ----
#define OFF_PSI2S 0           // 65536 zeroed (atomic)
#define OFF_SCOV  65536       // 65536 zeroed (atomic)
#define OFF_GA    131072      // 65536 zeroed (atomic)
#define OFF_S     196608      // 16 scalars zeroed; [8] = done-counter
#define ZERO_CNT  196624
#define OFF_PSI1  196624      // 262144 N*M fp32
#define OFF_P1H   458768      // 131072 N*M bf16
#define OFF_GM    589840      // 262144 N*M fp32 (LOG2E-scaled)
#define OFF_F2    851984      // 32768  N*Q fp32 (LOG2E-scaled)
#define OFF_KM    884752      // 65536
#define OFF_KINV  950288      // 65536
#define OFF_KH    1015824     // 32768  M*M bf16
#define OFF_W1    1048592     // 65536
#define OFF_W     1114128     // 65536
#define OFF_T3    1179664     // 8192   M*D
#define OFF_ZB    1187856     // 4096   M*Q bf16
#define OFF_ABF   1191952     // 131072 N*M bf16
#define OFF_ABFT  1323024     // 131072 M*N bf16
#define OFF_BTJ   1454096     // 1048576 D*M*M bf16 [d][j][l]
#define OFF_BTL   2502672     // 1048576 D*M*M bf16 [d][l][j]
#define OFF_TMP   3551248     // 4194304 N*D*M bf16 [n][d][l]
// end = 7745552 floats = 31.0 MB

struct Params {
  const float *Xm, *Xv, *Z, *ls, *pvar, *pbeta, *qmu, *qs;
  float *psi1, *gm, *f2, *KM, *Kinv, *W1, *W, *t3;
  float *psi2s, *Scov, *GA, *Sv, *zarea;
  ushort *p1h, *Kh, *zb, *abf, *abfT, *Btj, *Btl, *tmp;
  float *outMean, *outVar, *outL;
};

__device__ __forceinline__ ushort f2bf(float x) {
  unsigned int u = __builtin_bit_cast(unsigned int, x);
  u += 0x7fffu + ((u >> 16) & 1u);
  return (ushort)(u >> 16);
}

// ================= Phase A =================
// [0,1024) stats | [1024,1280) Kmm | [1280,1377) zero | [1377,1385) zb
// [1385,2409) btj | [2409,3433) btl
__global__ __launch_bounds__(256) void kA(Params p) {
  __shared__ __align__(16) float sb[2112];
  int bx = blockIdx.x, tid = threadIdx.x;
  if (bx < N_PTS) {
    int n = bx;
    float* w1s = sb; float* w1mu = sb+32; float* w2s = sb+64; float* w2mu = sb+96;
    float* rl2s = sb+128; float* la1 = sb+160; float* a1s = sb+192;
    float* la2 = sb+224; float* a2s = sb+256;
    float v = *p.pvar;
    if (tid < QD) {
      int q = tid;
      float s = p.Xv[n*QD+q], mu = p.Xm[n*QD+q], l = p.ls[q], l2 = l*l;
      float rl2 = 1.f/l2;
      float d1 = l2 + s, d2 = l2 + 2.f*s;
      float iw1 = 1.f/d1, iw2 = 1.f/d2;
      w1s[q] = iw1; w1mu[q] = iw1*mu; w2s[q] = iw2; w2mu[q] = iw2*mu; rl2s[q] = rl2;
      la1[q] = logf(d1*rl2); a1s[q] = mu*mu*iw1;
      la2[q] = logf(d2*rl2); a2s[q] = mu*mu*iw2;
      p.f2[n*QD+q] = LOG2E*0.5f*(rl2 - iw2);
    }
    __syncthreads();
    if (tid == 0) {
      float s1=0, s2=0, s3=0, s4=0;
      for (int q = 0; q < QD; q++) { s1 += la1[q]; s2 += a1s[q]; s3 += la2[q]; s4 += a2s[q]; }
      sb[288] = -0.5f*(s1 + s2);
      sb[289] = 2.f*logf(v) - 0.5f*s3 - s4;
    }
    __syncthreads();
    float c1sh = sb[288], c2sh = sb[289];
    int m = tid;
    float b1 = 0, c1a = 0, eb = 0, ec = 0, zsq = 0;
    #pragma unroll
    for (int q4 = 0; q4 < QD; q4 += 4) {
      float4 z4 = *(const float4*)&p.Z[m*QD + q4];
      float z, zz;
      z = z4.x; zz = z*z; b1 += w1mu[q4+0]*z; c1a += w1s[q4+0]*zz; eb += w2mu[q4+0]*z; ec += w2s[q4+0]*zz; zsq += rl2s[q4+0]*zz;
      z = z4.y; zz = z*z; b1 += w1mu[q4+1]*z; c1a += w1s[q4+1]*zz; eb += w2mu[q4+1]*z; ec += w2s[q4+1]*zz; zsq += rl2s[q4+1]*zz;
      z = z4.z; zz = z*z; b1 += w1mu[q4+2]*z; c1a += w1s[q4+2]*zz; eb += w2mu[q4+2]*z; ec += w2s[q4+2]*zz; zsq += rl2s[q4+2]*zz;
      z = z4.w; zz = z*z; b1 += w1mu[q4+3]*z; c1a += w1s[q4+3]*zz; eb += w2mu[q4+3]*z; ec += w2s[q4+3]*zz; zsq += rl2s[q4+3]*zz;
    }
    float pv = v * __expf(c1sh + b1 - 0.5f*c1a);
    p.psi1[n*MI + m] = pv;
    p.p1h[n*MI + m] = f2bf(pv);
    p.gm[n*MI + m] = LOG2E*(0.5f*c2sh + (eb - 0.25f*ec) - 0.25f*zsq);
  } else if (bx < N_PTS + MI) {
    int m = bx - N_PTS;
    if (tid < QD) { float l = p.ls[tid]; sb[tid] = 1.f/(l*l); }
    __syncthreads();
    int k = tid;
    float acc = 0;
    #pragma unroll
    for (int q4 = 0; q4 < QD; q4 += 4) {
      float4 zm = *(const float4*)&p.Z[m*QD + q4];
      float4 zk = *(const float4*)&p.Z[k*QD + q4];
      float d;
      d = zm.x - zk.x; acc += d*d*sb[q4+0];
      d = zm.y - zk.y; acc += d*d*sb[q4+1];
      d = zm.z - zk.z; acc += d*d*sb[q4+2];
      d = zm.w - zk.w; acc += d*d*sb[q4+3];
    }
    float v = *p.pvar;
    p.KM[m*MI + k] = v*__expf(-0.5f*acc) + (m == k ? JITTER : 0.f);
  } else if (bx < 1377) {
    int base = (bx - 1280)*2048 + tid*8;
    #pragma unroll
    for (int e = 0; e < 8; e++) {
      int i = base + e;
      if (i < ZERO_CNT) p.zarea[i] = 0.f;
    }
  } else if (bx < 1385) {
    int i = ((bx - 1377)*256 + tid)*4;
    float4 z = *(const float4*)&p.Z[i];
    uint2 o;
    o.x = (unsigned)f2bf(z.x) | ((unsigned)f2bf(z.y) << 16);
    o.y = (unsigned)f2bf(z.z) | ((unsigned)f2bf(z.w) << 16);
    *(uint2*)&p.zb[i] = o;
  } else if (bx < 2409) {
    int idx = bx - 1385;
    int j = idx & 255, l0 = (idx >> 8)*64;
    int base = j*8192 + l0*32;
    #pragma unroll
    for (int e = 0; e < 8; e++) {
      int lin = e*256 + tid;
      sb[(lin >> 5)*33 + (lin & 31)] = p.qs[base + lin];
    }
    __syncthreads();
    int ll = tid & 63, kq = tid >> 6;
    int l = l0 + ll;
    #pragma unroll
    for (int w8 = 0; w8 < 8; w8++) {
      int k = kq*8 + w8;
      float v = (l <= j) ? sb[ll*33 + k] : 0.f;
      p.Btj[k*65536 + j*256 + l] = f2bf(v);
    }
  } else {
    int idx = bx - 2409;
    int l = idx & 255, j0 = (idx >> 8)*64;
    {
      int jr = tid >> 2, d8 = (tid & 3)*8;
      const float* src = &p.qs[(j0+jr)*8192 + l*32 + d8];
      float4 a = *(const float4*)src, b = *(const float4*)(src+4);
      float* dst = &sb[jr*33 + d8];
      dst[0]=a.x; dst[1]=a.y; dst[2]=a.z; dst[3]=a.w;
      dst[4]=b.x; dst[5]=b.y; dst[6]=b.z; dst[7]=b.w;
    }
    __syncthreads();
    int d = tid >> 3, j8 = (tid & 7)*8;
    unsigned int pk[4];
    #pragma unroll
    for (int q = 0; q < 4; q++) {
      int ja = j0 + j8 + q*2;
      float va = (l <= ja)   ? sb[(j8 + q*2)*33 + d]     : 0.f;
      float vb = (l <= ja+1) ? sb[(j8 + q*2 + 1)*33 + d] : 0.f;
      pk[q] = (unsigned)f2bf(va) | ((unsigned)f2bf(vb) << 16);
    }
    *(uint4*)&p.Btl[d*65536 + l*256 + j0 + j8] = make_uint4(pk[0], pk[1], pk[2], pk[3]);
  }
}

// ================= Phase B =================
// [0,1024) psi2 | [1024,1088) NS: G=E@E, Kinv = s(2I - sKM + G) | [1088,1216) scov
__global__ __launch_bounds__(256) void kB(Params p) {
  __shared__ __align__(16) float sb[2560];
  int bx = blockIdx.x, tid = threadIdx.x;
  int lane = tid & 63, w = tid >> 6, l15 = lane & 15, quad = lane >> 4;
  if (bx < 1024) {
    int tile = bx & 15;
    int tm = (tile & 3)*64, tk = (tile >> 2)*64;
    int n0 = (bx >> 4)*16;
    float zm[8];
    {
      const float* zr = &p.Z[(tm + w*16 + l15)*32 + quad*8];
      float4 aq = *(const float4*)zr, bq = *(const float4*)(zr + 4);
      zm[0]=aq.x; zm[1]=aq.y; zm[2]=aq.z; zm[3]=aq.w;
      zm[4]=bq.x; zm[5]=bq.y; zm[6]=bq.z; zm[7]=bq.w;
    }
    short8 bfr[4];
    #pragma unroll
    for (int c = 0; c < 4; c++)
      bfr[c] = *(const short8*)&p.zb[(tk + c*16 + l15)*32 + quad*8];
    float accs[4][4] = {};
    #pragma unroll 1
    for (int nl = 0; nl < 16; nl++) {
      int n = n0 + nl;
      const float* fp = &p.f2[n*32 + quad*8];
      float4 f0 = *(const float4*)fp, f1 = *(const float4*)(fp + 4);
      unsigned q0 = (unsigned)f2bf(f0.x*zm[0]) | ((unsigned)f2bf(f0.y*zm[1]) << 16);
      unsigned q1 = (unsigned)f2bf(f0.z*zm[2]) | ((unsigned)f2bf(f0.w*zm[3]) << 16);
      unsigned q2 = (unsigned)f2bf(f1.x*zm[4]) | ((unsigned)f2bf(f1.y*zm[5]) << 16);
      unsigned q3 = (unsigned)f2bf(f1.z*zm[6]) | ((unsigned)f2bf(f1.w*zm[7]) << 16);
      uint4 u4 = make_uint4(q0, q1, q2, q3);
      short8 af = __builtin_bit_cast(short8, u4);
      float4 gmv = *(const float4*)&p.gm[n*256 + tm + w*16 + quad*4];
      float gmr[4] = {gmv.x, gmv.y, gmv.z, gmv.w};
      #pragma unroll
      for (int c = 0; c < 4; c++) {
        floatx4 zz = {0.f, 0.f, 0.f, 0.f};
        floatx4 g = __builtin_amdgcn_mfma_f32_16x16x32_bf16(af, bfr[c], zz, 0, 0, 0);
        float gk = p.gm[n*256 + tk + c*16 + l15];
        #pragma unroll
        for (int r = 0; r < 4; r++)
          accs[c][r] += __builtin_exp2f(g[r] + gmr[r] + gk);
      }
    }
    #pragma unroll
    for (int c = 0; c < 4; c++)
      #pragma unroll
      for (int r = 0; r < 4; r++)
        atomicAdd(&p.psi2s[(tm + w*16 + quad*4 + r)*256 + tk + c*16 + l15], accs[c][r]);
  } else if (bx < 1088) {
    // G = E@E (E = s*KM - I), epilogue Kinv = s*(2I - s*KM + G), Kh = bf16(Kinv)
    int idx = bx - 1024;
    int col0 = (idx & 7)*32, row0 = (idx >> 3)*32;
    float s = 1.f/(p.pvar[0] + JITTER);
    float* As = sb; float* Bs = sb + 1056;
    int r2 = (tid >> 4)*2, c2 = (tid & 15)*2;
    float a00=0, a01=0, a10=0, a11=0;
    int sr = tid >> 3, sq = (tid & 7)*4;
    for (int kc = 0; kc < 256; kc += 32) {
      int ar = row0 + sr;
      float4 av = *(const float4*)&p.KM[ar*MI + kc + sq];
      av.x = s*av.x - (ar == kc+sq+0 ? 1.f : 0.f);
      av.y = s*av.y - (ar == kc+sq+1 ? 1.f : 0.f);
      av.z = s*av.z - (ar == kc+sq+2 ? 1.f : 0.f);
      av.w = s*av.w - (ar == kc+sq+3 ? 1.f : 0.f);
      As[(sq+0)*33 + sr] = av.x; As[(sq+1)*33 + sr] = av.y;
      As[(sq+2)*33 + sr] = av.z; As[(sq+3)*33 + sr] = av.w;
      int br = kc + sr;
      float4 bv = *(const float4*)&p.KM[br*MI + col0 + sq];
      bv.x = s*bv.x - (br == col0+sq+0 ? 1.f : 0.f);
      bv.y = s*bv.y - (br == col0+sq+1 ? 1.f : 0.f);
      bv.z = s*bv.z - (br == col0+sq+2 ? 1.f : 0.f);
      bv.w = s*bv.w - (br == col0+sq+3 ? 1.f : 0.f);
      Bs[sr*33 + sq+0] = bv.x; Bs[sr*33 + sq+1] = bv.y;
      Bs[sr*33 + sq+2] = bv.z; Bs[sr*33 + sq+3] = bv.w;
      __syncthreads();
      #pragma unroll
      for (int kk = 0; kk < 32; kk++) {
        float x0 = As[kk*33 + r2], x1 = As[kk*33 + r2 + 1];
        float y0 = Bs[kk*33 + c2], y1 = Bs[kk*33 + c2 + 1];
        a00 += x0*y0; a01 += x0*y1; a10 += x1*y0; a11 += x1*y1;
      }
      __syncthreads();
    }
    float vals[2][2] = {{a00, a01}, {a10, a11}};
    #pragma unroll
    for (int i = 0; i < 2; i++)
      #pragma unroll
      for (int j = 0; j < 2; j++) {
        int R = row0 + r2 + i, C = col0 + c2 + j;
        float kv = s*(vals[i][j] + (R == C ? 2.f : 0.f) - s*p.KM[R*MI + C]);
        p.Kinv[R*MI + C] = kv;
        p.Kh[R*MI + C] = f2bf(kv);
      }
  } else {
    int idx = bx - 1088;
    int tile = idx & 15;
    int i0 = (tile & 3)*64, j0 = (tile >> 2)*64;
    int d0 = (idx >> 4)*4;
    ushort* Au = (ushort*)sb; ushort* Bu = Au + 2560;
    floatx4 accs[4];
    #pragma unroll
    for (int c = 0; c < 4; c++) accs[c] = (floatx4){0.f,0.f,0.f,0.f};
    int sr = tid >> 2, sq = (tid & 3)*8;
    for (int dd = 0; dd < 4; dd++) {
      const ushort* base = p.Btj + (size_t)(d0 + dd)*65536;
      for (int kc = 0; kc < 256; kc += 32) {
        __syncthreads();
        *(uint4*)&Au[sr*LSU + sq] = *(const uint4*)&base[(i0+sr)*256 + kc + sq];
        *(uint4*)&Bu[sr*LSU + sq] = *(const uint4*)&base[(j0+sr)*256 + kc + sq];
        __syncthreads();
        short8 af = *(const short8*)&Au[(w*16 + l15)*LSU + quad*8];
        #pragma unroll
        for (int c = 0; c < 4; c++) {
          short8 bfv = *(const short8*)&Bu[(c*16 + l15)*LSU + quad*8];
          accs[c] = __builtin_amdgcn_mfma_f32_16x16x32_bf16(af, bfv, accs[c], 0, 0, 0);
        }
      }
    }
    #pragma unroll
    for (int c = 0; c < 4; c++)
      #pragma unroll
      for (int r = 0; r < 4; r++)
        atomicAdd(&p.Scov[(i0 + w*16 + quad*4 + r)*256 + j0 + c*16 + l15], accs[c][r]);
  }
}

// ================= Phase D =================
// [0,64) abf = psi1@Kinv (bf16 MFMA) | [64,96) t3 = Kinv@qmu | [96,160) W1 = Kinv@psi2s
__global__ __launch_bounds__(256) void kD(Params p) {
  __shared__ __align__(16) float sb[2560];
  int bx = blockIdx.x, tid = threadIdx.x;
  if (bx < 64) {
    int j0 = (bx & 3)*64, n0 = (bx >> 2)*64;
    int lane = tid & 63, w = tid >> 6, l15 = lane & 15, quad = lane >> 4;
    ushort* Ah = (ushort*)sb; ushort* Bh = Ah + 2560;
    floatx4 acc[4];
    #pragma unroll
    for (int c = 0; c < 4; c++) acc[c] = (floatx4){0.f,0.f,0.f,0.f};
    int sr = tid >> 2, sq = (tid & 3)*8;
    for (int kc = 0; kc < 256; kc += 32) {
      __syncthreads();
      *(uint4*)&Ah[sr*LSU + sq] = *(const uint4*)&p.p1h[(n0+sr)*256 + kc + sq];
      *(uint4*)&Bh[sr*LSU + sq] = *(const uint4*)&p.Kh[(j0+sr)*256 + kc + sq];
      __syncthreads();
      short8 ah = *(const short8*)&Ah[(w*16 + l15)*LSU + quad*8];
      #pragma unroll
      for (int c = 0; c < 4; c++) {
        short8 bh = *(const short8*)&Bh[(c*16 + l15)*LSU + quad*8];
        acc[c] = __builtin_amdgcn_mfma_f32_16x16x32_bf16(ah, bh, acc[c], 0, 0, 0);
      }
    }
    #pragma unroll
    for (int c = 0; c < 4; c++)
      #pragma unroll
      for (int r = 0; r < 4; r++) {
        int n = n0 + w*16 + quad*4 + r, j = j0 + c*16 + l15;
        ushort hv = f2bf(acc[c][r]);
        p.abf[n*256 + j] = hv;
        p.abfT[j*1024 + n] = hv;
      }
  } else if (bx < 96) {
    // t3 rows [rbase, rbase+8)
    int rbase = (bx - 64)*8;
    int c = tid & 31, r = rbase + (tid >> 5);
    float acc = 0;
    for (int k = 0; k < 256; k += 4) {
      float4 a4 = *(const float4*)&p.Kinv[r*256 + k];
      acc += a4.x*p.qmu[(k+0)*32+c] + a4.y*p.qmu[(k+1)*32+c]
           + a4.z*p.qmu[(k+2)*32+c] + a4.w*p.qmu[(k+3)*32+c];
    }
    p.t3[r*32 + c] = acc;
  } else {
    // W1 = Kinv @ psi2s (fp32, 32x32 tile)
    int idx = bx - 96;
    int col0 = (idx & 7)*32, row0 = (idx >> 3)*32;
    float* As = sb; float* Bs = sb + 1089;
    int r2 = (tid >> 4)*2, c2 = (tid & 15)*2;
    float a00=0, a01=0, a10=0, a11=0;
    int sr = tid >> 3, sq = (tid & 7)*4;
    for (int kc = 0; kc < 256; kc += 32) {
      float4 av = *(const float4*)&p.Kinv[(row0+sr)*MI + kc + sq];
      As[(sq+0)*33 + sr] = av.x; As[(sq+1)*33 + sr] = av.y;
      As[(sq+2)*33 + sr] = av.z; As[(sq+3)*33 + sr] = av.w;
      float4 bv = *(const float4*)&p.psi2s[(kc+sr)*MI + col0 + sq];
      Bs[sr*33 + sq+0] = bv.x; Bs[sr*33 + sq+1] = bv.y;
      Bs[sr*33 + sq+2] = bv.z; Bs[sr*33 + sq+3] = bv.w;
      __syncthreads();
      #pragma unroll
      for (int kk = 0; kk < 32; kk++) {
        float x0 = As[kk*33 + r2], x1 = As[kk*33 + r2 + 1];
        float y0 = Bs[kk*33 + c2], y1 = Bs[kk*33 + c2 + 1];
        a00 += x0*y0; a01 += x0*y1; a10 += x1*y0; a11 += x1*y1;
      }
      __syncthreads();
    }
    int ro = (row0 + r2)*MI + col0 + c2;
    p.W1[ro] = a00; p.W1[ro+1] = a01; p.W1[ro+MI] = a10; p.W1[ro+MI+1] = a11;
  }
}

// ================= Phase E =================
// [0,2048) tmp = abf @ BtlFlat^T (bf16 GEMM 1024x8192x256) | [2048,2112) GA gram
// [2112,2176) W = W1@Kinv
__global__ __launch_bounds__(256) void kE(Params p) {
  __shared__ __align__(16) float sb[2560];
  int bx = blockIdx.x, tid = threadIdx.x;
  int lane = tid & 63, w = tid >> 6, l15 = lane & 15, quad = lane >> 4;
  if (bx < 2048) {
    int n0 = (bx & 15)*64;
    int c0 = (bx >> 4)*64;   // flat col over (d,l): d = c0>>8 constant per tile
    ushort* As = (ushort*)sb; ushort* Bs = As + 2560;
    floatx4 acc[4];
    #pragma unroll
    for (int c = 0; c < 4; c++) acc[c] = (floatx4){0.f,0.f,0.f,0.f};
    int sr = tid >> 2, sq = (tid & 3)*8;
    for (int kc = 0; kc < 256; kc += 32) {
      __syncthreads();
      *(uint4*)&As[sr*LSU + sq] = *(const uint4*)&p.abf[(n0+sr)*256 + kc + sq];
      *(uint4*)&Bs[sr*LSU + sq] = *(const uint4*)&p.Btl[(size_t)(c0+sr)*256 + kc + sq];
      __syncthreads();
      short8 af = *(const short8*)&As[(w*16 + l15)*LSU + quad*8];
      #pragma unroll
      for (int c = 0; c < 4; c++) {
        short8 b = *(const short8*)&Bs[(c*16 + l15)*LSU + quad*8];
        acc[c] = __builtin_amdgcn_mfma_f32_16x16x32_bf16(af, b, acc[c], 0, 0, 0);
      }
    }
    #pragma unroll
    for (int c = 0; c < 4; c++)
      #pragma unroll
      for (int r = 0; r < 4; r++) {
        int n = n0 + w*16 + quad*4 + r, cc = c0 + c*16 + l15;
        p.tmp[(size_t)n*8192 + cc] = f2bf(acc[c][r]);
      }
  } else if (bx < 2112) {
    int idx = bx - 2048;
    int tile = idx & 15;
    int i0 = (tile & 3)*64, j0 = (tile >> 2)*64;
    int nc0 = (idx >> 4)*256;
    ushort* Au = (ushort*)sb; ushort* Bu = Au + 2560;
    floatx4 accs[4];
    #pragma unroll
    for (int c = 0; c < 4; c++) accs[c] = (floatx4){0.f,0.f,0.f,0.f};
    int sr = tid >> 2, sq = (tid & 3)*8;
    for (int kc = 0; kc < 256; kc += 32) {
      __syncthreads();
      *(uint4*)&Au[sr*LSU + sq] = *(const uint4*)&p.abfT[(i0+sr)*1024 + nc0 + kc + sq];
      *(uint4*)&Bu[sr*LSU + sq] = *(const uint4*)&p.abfT[(j0+sr)*1024 + nc0 + kc + sq];
      __syncthreads();
      short8 af = *(const short8*)&Au[(w*16 + l15)*LSU + quad*8];
      #pragma unroll
      for (int c = 0; c < 4; c++) {
        short8 bfv = *(const short8*)&Bu[(c*16 + l15)*LSU + quad*8];
        accs[c] = __builtin_amdgcn_mfma_f32_16x16x32_bf16(af, bfv, accs[c], 0, 0, 0);
      }
    }
    #pragma unroll
    for (int c = 0; c < 4; c++)
      #pragma unroll
      for (int r = 0; r < 4; r++)
        atomicAdd(&p.GA[(i0 + w*16 + quad*4 + r)*256 + j0 + c*16 + l15], accs[c][r]);
  } else {
    // W = W1 @ Kinv (fp32, 32x32 tile)
    int idx = bx - 2112;
    int col0 = (idx & 7)*32, row0 = (idx >> 3)*32;
    float* As = sb; float* Bs = sb + 1089;
    int r2 = (tid >> 4)*2, c2 = (tid & 15)*2;
    float a00=0, a01=0, a10=0, a11=0;
    int sr = tid >> 3, sq = (tid & 7)*4;
    for (int kc = 0; kc < 256; kc += 32) {
      float4 av = *(const float4*)&p.W1[(row0+sr)*MI + kc + sq];
      As[(sq+0)*33 + sr] = av.x; As[(sq+1)*33 + sr] = av.y;
      As[(sq+2)*33 + sr] = av.z; As[(sq+3)*33 + sr] = av.w;
      float4 bv = *(const float4*)&p.Kinv[(kc+sr)*MI + col0 + sq];
      Bs[sr*33 + sq+0] = bv.x; Bs[sr*33 + sq+1] = bv.y;
      Bs[sr*33 + sq+2] = bv.z; Bs[sr*33 + sq+3] = bv.w;
      __syncthreads();
      #pragma unroll
      for (int kk = 0; kk < 32; kk++) {
        float x0 = As[kk*33 + r2], x1 = As[kk*33 + r2 + 1];
        float y0 = Bs[kk*33 + c2], y1 = Bs[kk*33 + c2 + 1];
        a00 += x0*y0; a01 += x0*y1; a10 += x1*y0; a11 += x1*y1;
      }
      __syncthreads();
    }
    int ro = (row0 + r2)*MI + col0 + c2;
    p.W[ro] = a00; p.W[ro+1] = a01; p.W[ro+MI] = a10; p.W[ro+MI+1] = a11;
  }
}

// ================= Phase F =================
// [0,256) fvar | [256,384) forward_mean = psi1@t3 | [384,608) reductions + finalize
__global__ __launch_bounds__(256) void kF(Params p) {
  __shared__ float red[4];
  int bx = blockIdx.x, tid = threadIdx.x;
  if (bx < 256) {
    int lane = tid & 63, w = tid >> 6;
    int n = bx*4 + w;
    int l15 = lane & 15, quad = lane >> 4;
    floatx4 acc[2][2];
    #pragma unroll
    for (int i = 0; i < 2; i++)
      #pragma unroll
      for (int j = 0; j < 2; j++) acc[i][j] = (floatx4){0.f,0.f,0.f,0.f};
    size_t base = (size_t)n*8192;
    #pragma unroll 1
    for (int s8 = 0; s8 < 8; s8++) {
      int off = s8*32 + quad*8;
      short8 h0 = *(const short8*)&p.tmp[base + l15*256 + off];
      short8 h1 = *(const short8*)&p.tmp[base + (16 + l15)*256 + off];
      acc[0][0] = __builtin_amdgcn_mfma_f32_16x16x32_bf16(h0, h0, acc[0][0], 0,0,0);
      acc[0][1] = __builtin_amdgcn_mfma_f32_16x16x32_bf16(h0, h1, acc[0][1], 0,0,0);
      acc[1][0] = __builtin_amdgcn_mfma_f32_16x16x32_bf16(h1, h0, acc[1][0], 0,0,0);
      acc[1][1] = __builtin_amdgcn_mfma_f32_16x16x32_bf16(h1, h1, acc[1][1], 0,0,0);
    }
    float ib = 1.f / (*p.pbeta);
    #pragma unroll
    for (int I = 0; I < 2; I++)
      #pragma unroll
      for (int J = 0; J < 2; J++)
        #pragma unroll
        for (int r = 0; r < 4; r++) {
          int row = I*16 + quad*4 + r, col = J*16 + l15;
          p.outVar[(size_t)n*1024 + row*32 + col] = acc[I][J][r] + (row == col ? ib : 0.f);
        }
  } else if (bx < 384) {
    int rbase = (bx - 256)*8;
    int c = tid & 31, r = rbase + (tid >> 5);
    float acc = 0;
    for (int k = 0; k < 256; k += 4) {
      float4 a4 = *(const float4*)&p.psi1[r*256 + k];
      acc += a4.x*p.t3[(k+0)*32+c] + a4.y*p.t3[(k+1)*32+c]
           + a4.z*p.t3[(k+2)*32+c] + a4.w*p.t3[(k+3)*32+c];
    }
    p.outMean[r*32 + c] = acc;
  } else {
    int idx = bx - 384;
    int seg = idx >> 5;
    int i0 = (idx & 31)*256 + tid;
    const int stride = 32*256;
    float s = 0;
    int target = 0;
    if (seg == 0) { for (int i = i0; i < 65536; i += stride) s += p.Kinv[i]*p.psi2s[i]; target = 0; }
    else if (seg == 1) { for (int i = i0; i < 8192; i += stride) s += p.qmu[i]*p.t3[i]; target = 1; }
    else if (seg == 2) { for (int i = i0; i < 65536; i += stride) s += p.Kinv[i]*p.Scov[i]; target = 2; }
    else if (seg == 3) {
      float invc = 1.f/(*p.pvar + JITTER);
      for (int i = i0; i < 65536; i += stride) {
        int r = i >> 8, c = i & 255;
        if (r != c) { float e = p.KM[i]*invc; s += e*e; }
      }
      target = 4;
    }
    else if (seg == 4) {
      for (int i = i0; i < MI*DOUT; i += stride) {
        int m = i >> 5, k = i & 31;
        float dq = p.qs[m*8224 + k];   // (m*256+m)*32 + k
        s += logf(dq*dq);
      }
      target = 5;
    }
    else if (seg == 5) {
      // sum W . (Scov + qmu qmu^T)
      for (int i = i0; i < 65536; i += stride) {
        int r = i >> 8, c = i & 255;
        float qq = 0;
        #pragma unroll
        for (int d = 0; d < DOUT; d++) qq += p.qmu[r*DOUT + d]*p.qmu[c*DOUT + d];
        s += p.W[i]*(p.Scov[i] + qq);
      }
      target = 6;
    }
    else {
      // sum GA . (Scov + qmu qmu^T)
      for (int i = i0; i < 65536; i += stride) {
        int r = i >> 8, c = i & 255;
        float qq = 0;
        #pragma unroll
        for (int d = 0; d < DOUT; d++) qq += p.qmu[r*DOUT + d]*p.qmu[c*DOUT + d];
        s += p.GA[i]*(p.Scov[i] + qq);
      }
      target = 7;
    }
    #pragma unroll
    for (int off = 32; off >= 1; off >>= 1) s += __shfl_down(s, off, 64);
    if ((tid & 63) == 0) red[tid >> 6] = s;
    __syncthreads();
    if (tid == 0) {
      float bs = red[0] + red[1] + red[2] + red[3];
      atomicAdd(&p.Sv[target], bs);
      __threadfence();
      unsigned prev = atomicAdd((unsigned int*)&p.Sv[8], 1u);
      if (prev == 223u) {
        float S0 = atomicAdd(&p.Sv[0], 0.f);
        float S1 = atomicAdd(&p.Sv[1], 0.f);
        float S2 = atomicAdd(&p.Sv[2], 0.f);
        float S4 = atomicAdd(&p.Sv[4], 0.f);
        float S5 = atomicAdd(&p.Sv[5], 0.f);
        float S6 = atomicAdd(&p.Sv[6], 0.f);
        float S7 = atomicAdd(&p.Sv[7], 0.f);
        float v = *p.pvar, b = *p.pbeta;
        float trace = (float)N_PTS * v - S0;
        float lml = -0.5f * b * (float)DOUT * trace;
        float c = v + JITTER;
        float logdetK = (float)MI * logf(c) - 0.5f * S4;
        float kl = 0.5f*(S1 + S2 - (float)(MI*DOUT) + (float)DOUT*logdetK - S5);
        lml -= kl;
        lml -= 0.5f * b * (S6 - S7);
        p.outL[0] = lml;
      }
    }
  }
}

extern "C" void kernel_launch(void* const* d_in, const int* in_sizes, int n_in,
                              void* d_out, int out_size, void* d_ws, size_t ws_size,
                              hipStream_t stream) {
  (void)in_sizes; (void)n_in; (void)out_size; (void)ws_size;
  float* out = (float*)d_out;
  float* ws  = (float*)d_ws;

  Params p;
  p.Xm = (const float*)d_in[0];
  p.Xv = (const float*)d_in[1];
  p.Z  = (const float*)d_in[2];
  p.qmu = (const float*)d_in[3];
  p.qs  = (const float*)d_in[4];
  p.ls  = (const float*)d_in[5];
  p.pvar  = (const float*)d_in[6];
  p.pbeta = (const float*)d_in[7];
  p.psi2s = ws + OFF_PSI2S;
  p.Scov  = ws + OFF_SCOV;
  p.GA    = ws + OFF_GA;
  p.Sv    = ws + OFF_S;
  p.zarea = ws;
  p.psi1  = ws + OFF_PSI1;
  p.p1h   = (ushort*)(ws + OFF_P1H);
  p.gm    = ws + OFF_GM;
  p.f2    = ws + OFF_F2;
  p.KM    = ws + OFF_KM;
  p.Kinv  = ws + OFF_KINV;
  p.Kh    = (ushort*)(ws + OFF_KH);
  p.W1    = ws + OFF_W1;
  p.W     = ws + OFF_W;
  p.t3    = ws + OFF_T3;
  p.zb    = (ushort*)(ws + OFF_ZB);
  p.abf   = (ushort*)(ws + OFF_ABF);
  p.abfT  = (ushort*)(ws + OFF_ABFT);
  p.Btj   = (ushort*)(ws + OFF_BTJ);
  p.Btl   = (ushort*)(ws + OFF_BTL);
  p.tmp   = (ushort*)(ws + OFF_TMP);
  p.outMean = out;
  p.outVar  = out + 32768;
  p.outL    = out + 32768 + 1048576;

  kA<<<3433, 256, 0, stream>>>(p);
  kB<<<1216, 256, 0, stream>>>(p);
  kD<<<160, 256, 0, stream>>>(p);
  kE<<<2176, 256, 0, stream>>>(p);
  kF<<<608, 256, 0, stream>>>(p);
}